// Round 12
// baseline (306.468 us; speedup 1.0000x reference)
//
#include <hip/hip_runtime.h>

typedef _Float16 f16x8 __attribute__((ext_vector_type(8)));
typedef float    f32x4 __attribute__((ext_vector_type(4)));

static __device__ inline f16x8 f16x8_zero() {
    f16x8 v;
#pragma unroll
    for (int j = 0; j < 8; ++j) v[j] = (_Float16)0.f;
    return v;
}

// ---------------------------------------------------------------------------
// Merged weight prep (one launch).
// conv1 split-f16: k=0..8 hi(w), 9..17 hi(w), 18..26 lo(w), 27..31 zero
//   (pairs with A rows {hi,lo,hi} -> full fp32 accuracy).
// convN: fp32 OIHW -> f16 [ch][tap][COUT][32k] (zero-pad past CIN).
// ---------------------------------------------------------------------------
static __device__ inline void prep1_elem(const float* __restrict__ w,
                                         _Float16* __restrict__ dst, int t) {
    int co = t >> 5, k = t & 31;
    _Float16 r = (_Float16)0.f;
    if (k < 27) {
        int q = k / 9, tap = k - q * 9;
        float wv = w[co * 9 + tap];
        _Float16 hi = (_Float16)wv;
        r = (q == 2) ? (_Float16)(wv - (float)hi) : hi;
    }
    dst[t] = r;
}

template<int CIN, int COUT>
static __device__ inline void prepN_elem(const float* __restrict__ w,
                                         _Float16* __restrict__ dst, int t) {
    int k = t & 31;
    int r = t >> 5;
    int co = r % COUT; r /= COUT;
    int tap = r % 9;
    int chh = r / 9;
    int ci  = chh * 32 + k;
    dst[t] = (ci < CIN) ? (_Float16)w[(co * CIN + ci) * 9 + tap] : (_Float16)0.f;
}

__global__ __launch_bounds__(256) void prep_all_k(
    const float* __restrict__ lw1, const float* __restrict__ sw1,
    const float* __restrict__ lw2, const float* __restrict__ lw3,
    const float* __restrict__ sw2, const float* __restrict__ sw3,
    _Float16* __restrict__ W1L, _Float16* __restrict__ W1S,
    _Float16* __restrict__ wp2, _Float16* __restrict__ wp3,
    _Float16* __restrict__ wp2s, _Float16* __restrict__ wp3s)
{
    int t = blockIdx.x * 256 + threadIdx.x;
    if (t < 1024)  { prep1_elem(lw1, W1L, t); return; }   t -= 1024;
    if (t < 512)   { prep1_elem(sw1, W1S, t); return; }   t -= 512;
    if (t < 18432) { prepN_elem<32, 64>(lw2, wp2, t);  return; }  t -= 18432;
    if (t < 73728) { prepN_elem<64, 128>(lw3, wp3, t); return; }  t -= 73728;
    if (t < 9216)  { prepN_elem<16, 32>(sw2, wp2s, t); return; }  t -= 9216;
    if (t < 18432) { prepN_elem<32, 64>(sw3, wp3s, t); return; }
}

// ---------------------------------------------------------------------------
// Zero the 1-px borders of the four padded NHWC intermediate buffers.
// ---------------------------------------------------------------------------
template<int H, int C>
static __device__ inline void zerob(_Float16* buf, int t) {
    constexpr int HP = H + 2, PB = 4 * H + 4, CU = C / 8;
    int cu = t % CU; int r = t / CU;
    int b = r / PB, p = r % PB;
    int row, col;
    if (p < 2 * HP) { row = (p < HP) ? 0 : (H + 1); col = p % HP; }
    else { int q = p - 2 * HP; row = 1 + (q >> 1); col = (q & 1) ? (H + 1) : 0; }
    *(f16x8*)&buf[(((size_t)b * HP + row) * HP + col) * C + cu * 8] = f16x8_zero();
}

__global__ __launch_bounds__(256) void zerob_all_k(
    _Float16* aL, _Float16* bL, _Float16* aS, _Float16* bS)
{
    int t = blockIdx.x * 256 + threadIdx.x;
    if (t < 132096) { zerob<128, 32>(aL, t); return; }  t -= 132096;
    if (t < 133120) { zerob<64, 64>(bL, t);  return; }  t -= 133120;
    if (t < 66048)  { zerob<128, 16>(aS, t); return; }  t -= 66048;
    if (t < 66560)  { zerob<64, 32>(bS, t);  return; }
}

// ---------------------------------------------------------------------------
// conv1 v2: CIN=1 fp32 in [B][256][256] -> conv+bias+relu+pool ->
// f16 padded NHWC [B][130][130][COUT]. K=27 split-f16 (fp32-exact).
// Tile 32x16 (M8, wave = 8 conv rows), 8192 blocks, 3 blocks/CU.
// STATS=true additionally computes mask global-stats over the block's
// 32x16 core from the staged f16 values (mask is 0/1 -> f16-exact) and
// merges one atomic set per block -> stats_k eliminated.
// ---------------------------------------------------------------------------
template<int COUT, bool STATS>
__global__ __launch_bounds__(256, 3) void conv1_mfma_k(
    const float* __restrict__ in, const _Float16* __restrict__ W1,
    const float* __restrict__ bias, _Float16* __restrict__ out,
    float* __restrict__ areaA, float* __restrict__ siA, float* __restrict__ sjA,
    int* __restrict__ miniA, int* __restrict__ maxiA,
    int* __restrict__ minjA, int* __restrict__ maxjA)
{
    constexpr int H = 256, TX = 16, TY = 8, NT = COUT / 16;

    __shared__ _Float16 sHL[1836];  // [0,612)=hi, [612,1224)=lo, [1224,1836)=0

    int blk  = blockIdx.x;
    int b    = blk / (TX * TY);
    int tile = blk % (TX * TY);
    int ty0  = (tile / TX) * 32;
    int tx0  = (tile % TX) * 16;
    int tid  = threadIdx.x;
    int wv   = tid >> 6, l = tid & 63, cl = l & 15, kg = l >> 4;

    for (int idx = tid; idx < 612; idx += 256) {
        int row = idx / 18, col = idx - row * 18;
        int gy = ty0 - 1 + row, gx = tx0 - 1 + col;
        float v = 0.f;
        if ((unsigned)gy < (unsigned)H && (unsigned)gx < (unsigned)H)
            v = in[((size_t)b * H + gy) * H + gx];
        _Float16 hi = (_Float16)v;
        sHL[idx]        = hi;
        sHL[612 + idx]  = (_Float16)(v - (float)hi);
        sHL[1224 + idx] = (_Float16)0.f;
    }
    __syncthreads();

    int off8[8];
#pragma unroll
    for (int j = 0; j < 8; ++j) {
        int k = kg * 8 + j;
        int q = k / 9;
        int t = k - q * 9;
        int region = (q == 1) ? 1 : ((q == 3) ? 2 : 0);
        off8[j] = region * 612 + (t / 3) * 18 + (t % 3) + cl;
    }

    f16x8 bf[NT];
#pragma unroll
    for (int nt = 0; nt < NT; ++nt)
        bf[nt] = *(const f16x8*)&W1[(nt * 16 + cl) * 32 + kg * 8];

    f32x4 acc[8][NT];
#pragma unroll
    for (int i = 0; i < 8; ++i)
#pragma unroll
        for (int nt = 0; nt < NT; ++nt) acc[i][nt] = (f32x4){0.f, 0.f, 0.f, 0.f};

#pragma unroll
    for (int i = 0; i < 8; ++i) {
        int R = wv * 8 + i;
        f16x8 af;
#pragma unroll
        for (int j = 0; j < 8; ++j) af[j] = sHL[off8[j] + R * 18];
#pragma unroll
        for (int nt = 0; nt < NT; ++nt)
            acc[i][nt] = __builtin_amdgcn_mfma_f32_16x16x32_f16(af, bf[nt], acc[i][nt], 0, 0, 0);
    }

    int py0 = ty0 >> 1, px0 = tx0 >> 1;
#pragma unroll
    for (int i2 = 0; i2 < 4; ++i2)
#pragma unroll
        for (int j2 = 0; j2 < 2; ++j2)
#pragma unroll
            for (int nt = 0; nt < NT; ++nt) {
                float bv = bias[nt * 16 + cl];
                float m = fmaxf(fmaxf(acc[2 * i2][nt][2 * j2], acc[2 * i2][nt][2 * j2 + 1]),
                                fmaxf(acc[2 * i2 + 1][nt][2 * j2], acc[2 * i2 + 1][nt][2 * j2 + 1]));
                float v = fmaxf(m + bv, 0.f);
                out[(((size_t)b * 130 + 1 + py0 + wv * 4 + i2) * 130 + 1 + px0 + kg * 2 + j2)
                    * COUT + nt * 16 + cl] = (_Float16)v;
            }

    if (STATS) {
        // stats over the 32x16 core; sHL unchanged since the stage barrier
        float area = 0.f, si = 0.f, sj = 0.f;
        int mini = 1 << 20, maxi = -1, minj = 1 << 20, maxj = -1;
#pragma unroll
        for (int k = 0; k < 2; ++k) {
            int lr = (tid >> 4) + k * 16;          // 0..31
            int lc = tid & 15;                     // 0..15
            float v = (float)sHL[(lr + 1) * 18 + (lc + 1)];
            if (v != 0.f) {
                int ii = ty0 + lr, jj = tx0 + lc;
                area += 1.f; si += (float)ii; sj += (float)jj;
                mini = min(mini, ii); maxi = max(maxi, ii);
                minj = min(minj, jj); maxj = max(maxj, jj);
            }
        }
#pragma unroll
        for (int off = 32; off > 0; off >>= 1) {
            area += __shfl_down(area, off);
            si   += __shfl_down(si, off);
            sj   += __shfl_down(sj, off);
            mini  = min(mini, __shfl_down(mini, off));
            maxi  = max(maxi, __shfl_down(maxi, off));
            minj  = min(minj, __shfl_down(minj, off));
            maxj  = max(maxj, __shfl_down(maxj, off));
        }
        __shared__ float rA[4], rI[4], rJ[4];
        __shared__ int   rmi[4], rMi[4], rmj[4], rMj[4];
        if (l == 0) {
            rA[wv] = area; rI[wv] = si; rJ[wv] = sj;
            rmi[wv] = mini; rMi[wv] = maxi; rmj[wv] = minj; rMj[wv] = maxj;
        }
        __syncthreads();
        if (tid == 0) {
            area = rA[0] + rA[1] + rA[2] + rA[3];
            si   = rI[0] + rI[1] + rI[2] + rI[3];
            sj   = rJ[0] + rJ[1] + rJ[2] + rJ[3];
            mini = min(min(rmi[0], rmi[1]), min(rmi[2], rmi[3]));
            maxi = max(max(rMi[0], rMi[1]), max(rMi[2], rMi[3]));
            minj = min(min(rmj[0], rmj[1]), min(rmj[2], rmj[3]));
            maxj = max(max(rMj[0], rMj[1]), max(rMj[2], rMj[3]));
            if (area > 0.f) {
                atomicAdd(&areaA[b], area);
                atomicAdd(&siA[b], si);
                atomicAdd(&sjA[b], sj);
                atomicMin(&miniA[b], mini);
                atomicMax(&maxiA[b], maxi);
                atomicMin(&minjA[b], minj);
                atomicMax(&maxjA[b], maxj);
            }
        }
    }
}

// ---------------------------------------------------------------------------
// convN v9 (= v8 minus the XCD swizzle, which doubled conv3 FETCH — r11).
// (256,2) is mandatory: M8N4 acc = 128 AGPR + 128 VGPR = full 256/wave
// budget (r10: (256,3) spills). XOR-swizzled unpadded LDS (conflicts = 0,
// r10). One block per (b, tile, co-group); NCH chunks: global->VGPR->
// swizzled ds_write, barrier, 9-tap MFMA loop, W per-lane from global
// (L2-hot, 2-slot rotation). Wave = 8 rows x 16 cols x NT*16 co.
// LDS unit u = pos*KU + q', KU=4: q'=q^((pos>>1)&3); KU=2: q'=q^((pos>>2)&1).
// POOL=false: cross-wave LDS reduce -> one non-atomic 64-partial store.
// ---------------------------------------------------------------------------
template<int CIN, int COUT, int H, bool POOL>
__global__ __launch_bounds__(256, 2) void convN_mfma_k(
    const _Float16* __restrict__ in, const _Float16* __restrict__ wp,
    const float* __restrict__ bias, void* __restrict__ outv)
{
    constexpr int HP  = H + 2;
    constexpr int TX  = H / 16, TY = H / 32, TT = TX * TY;
    constexpr int NT  = (COUT >= 64) ? 4 : COUT / 16;
    constexpr int NG  = COUT / (NT * 16);
    constexpr int NCH = (CIN + 31) / 32;
    constexpr int KU  = (CIN >= 32) ? 4 : 2;        // 16B units per pos
    constexpr int UNITS = 612 * KU;
    constexpr int NU  = (UNITS + 255) / 256;
    static_assert(H % 32 == 0 && COUT % 16 == 0, "");

    __shared__ _Float16 sA[UNITS * 8];              // unpadded, swizzled
    __shared__ float sRed[4][64];

    int tid = threadIdx.x;
    int wv = tid >> 6, l = tid & 63, cl = l & 15, kg = l >> 4;

    int blk  = blockIdx.x;
    int bb   = blk / (TT * NG);
    int rr   = blk % (TT * NG);
    int grp  = rr / TT;
    int tl   = rr % TT;
    int ty0  = (tl / TX) * 32, tx0 = (tl % TX) * 16;
    int cog0 = grp * NT * 16;

    f32x4 acc[8][NT];
#pragma unroll
    for (int i = 0; i < 8; ++i)
#pragma unroll
        for (int nt = 0; nt < NT; ++nt) acc[i][nt] = (f32x4){0.f, 0.f, 0.f, 0.f};

    const _Float16* ibase = in + (size_t)bb * HP * HP * CIN;

    for (int ch = 0; ch < NCH; ++ch) {
        if (ch) __syncthreads();
        // ---- stage: coalesced global reads, swizzled ds_write ----
#pragma unroll
        for (int k = 0; k < NU; ++k) {
            int u = k * 256 + tid;
            if (u < UNITS) {
                int pos, q;
                if (KU == 4) { pos = u >> 2; q = (u & 3) ^ ((pos >> 1) & 3); }
                else         { pos = u >> 1; q = (u & 1) ^ ((pos >> 2) & 1); }
                int row = pos / 18, col = pos - row * 18;
                f16x8 v = *(const f16x8*)&ibase[((size_t)(ty0 + row) * HP + tx0 + col) * CIN
                                                + ch * 32 + q * 8];
                *(f16x8*)&sA[(size_t)u * 8] = v;
            }
        }
        __syncthreads();

        const _Float16* wbase = wp + ((size_t)ch * 9 * COUT + cog0) * 32;
        f16x8 wreg[2][NT];
#pragma unroll
        for (int nt = 0; nt < NT; ++nt)
            wreg[0][nt] = *(const f16x8*)&wbase[(0 * COUT + nt * 16 + cl) * 32 + kg * 8];

#pragma unroll
        for (int tap = 0; tap < 9; ++tap) {
            if (tap < 8) {
#pragma unroll
                for (int nt = 0; nt < NT; ++nt)
                    wreg[(tap + 1) & 1][nt] =
                        *(const f16x8*)&wbase[((tap + 1) * COUT + nt * 16 + cl) * 32 + kg * 8];
            }
            int dy = tap / 3, dx = tap - dy * 3;
#pragma unroll
            for (int i = 0; i < 8; ++i) {
                int pos = (wv * 8 + i + dy) * 18 + cl + dx;
                int qq = (KU == 4) ? (kg ^ ((pos >> 1) & 3))
                                   : ((kg & 1) ^ ((pos >> 2) & 1));
                f16x8 af = *(const f16x8*)&sA[((size_t)pos * KU + qq) * 8];
#pragma unroll
                for (int nt = 0; nt < NT; ++nt)
                    acc[i][nt] = __builtin_amdgcn_mfma_f32_16x16x32_f16(
                        af, wreg[tap & 1][nt], acc[i][nt], 0, 0, 0);
            }
        }
    }

    if (POOL) {
        _Float16* out = (_Float16*)outv;
        constexpr int HP2 = H / 2 + 2;
        int py0 = ty0 >> 1, px0 = tx0 >> 1;
        float bv[NT];
#pragma unroll
        for (int nt = 0; nt < NT; ++nt) bv[nt] = bias[cog0 + nt * 16 + cl];
#pragma unroll
        for (int i2 = 0; i2 < 4; ++i2)
#pragma unroll
            for (int j2 = 0; j2 < 2; ++j2)
#pragma unroll
                for (int nt = 0; nt < NT; ++nt) {   // nt inner: line-clustered
                    float m = fmaxf(
                        fmaxf(acc[2 * i2][nt][2 * j2], acc[2 * i2][nt][2 * j2 + 1]),
                        fmaxf(acc[2 * i2 + 1][nt][2 * j2], acc[2 * i2 + 1][nt][2 * j2 + 1]));
                    float v = fmaxf(m + bv[nt], 0.f);
                    out[(((size_t)bb * HP2 + 1 + py0 + wv * 4 + i2) * HP2
                         + 1 + px0 + kg * 2 + j2) * COUT + cog0 + nt * 16 + cl]
                        = (_Float16)v;
                }
    } else {
        float sv[NT];
#pragma unroll
        for (int nt = 0; nt < NT; ++nt) {
            float bvv = bias[cog0 + nt * 16 + cl];
            float s = 0.f;
#pragma unroll
            for (int i = 0; i < 8; ++i)
#pragma unroll
                for (int r = 0; r < 4; ++r)
                    s += fmaxf(acc[i][nt][r] + bvv, 0.f);
            s += __shfl_xor(s, 16); s += __shfl_xor(s, 32);
            sv[nt] = s;
        }
        if (kg == 0) {
#pragma unroll
            for (int nt = 0; nt < NT; ++nt) sRed[wv][nt * 16 + cl] = sv[nt];
        }
        __syncthreads();
        if (tid < NT * 16) {
            float t4 = sRed[0][tid] + sRed[1][tid] + sRed[2][tid] + sRed[3][tid];
            ((float*)outv)[((size_t)bb * TT + tl) * COUT + cog0 + tid] = t4;
        }
    }
}

// ---------------------------------------------------------------------------
// Fused MLP head: reduces conv3 tile-partials (8 tiles each) + global_stats.
// ---------------------------------------------------------------------------
__global__ __launch_bounds__(256) void head_k(
    const float* __restrict__ PL,         // B x 8 x 128 (tile partial sums)
    const float* __restrict__ PS,         // B x 8 x 64
    const float* __restrict__ areaA, const float* __restrict__ siA,
    const float* __restrict__ sjA,
    const int* __restrict__ miniA, const int* __restrict__ maxiA,
    const int* __restrict__ minjA, const int* __restrict__ maxjA,
    const float* __restrict__ gw, const float* __restrict__ gb,
    const float* __restrict__ fpw1, const float* __restrict__ fpb1,
    const float* __restrict__ fpw2, const float* __restrict__ fpb2,
    const float* __restrict__ ffw1, const float* __restrict__ ffb1,
    const float* __restrict__ ffw2, const float* __restrict__ ffb2,
    float* __restrict__ out)              // B x 256
{
    int b = blockIdx.x, tid = threadIdx.x;
    __shared__ float comb[80], hid1[128], sf[64], fused[192], hid2[256];
    constexpr float INV = 1.f / 4096.f;

    if (tid < 64) {
        float s = 0.f;
#pragma unroll
        for (int t = 0; t < 8; ++t) s += PS[((size_t)b * 8 + t) * 64 + tid];
        comb[tid] = s * INV;
    }
    if (tid >= 64 && tid < 80) {
        int co = tid - 64;
        float st[6] = {0.f, 0.f, 0.f, 0.f, 0.f, 0.f};
        float area = areaA[b];
        if (area > 0.f) {
            float safe = fmaxf(area, 1.f);
            float h  = (float)(maxiA[b] - miniA[b]);
            float w2 = (float)(maxjA[b] - minjA[b]);
            st[0] = (siA[b] / safe) / 256.f;
            st[1] = (sjA[b] / safe) / 256.f;
            st[2] = h / 256.f; st[3] = w2 / 256.f;
            st[4] = area / 65536.f; st[5] = h * w2 / 65536.f;
        }
        float s = gb[co];
        for (int k = 0; k < 6; ++k) s += gw[co * 6 + k] * st[k];
        comb[tid] = s;
    }
    if (tid < 128) {
        float s = 0.f;
#pragma unroll
        for (int t = 0; t < 8; ++t) s += PL[((size_t)b * 8 + t) * 128 + tid];
        fused[tid] = s * INV;
    }
    __syncthreads();
    if (tid < 128) {
        float s = fpb1[tid];
        for (int k = 0; k < 80; ++k) s += fpw1[tid * 80 + k] * comb[k];
        hid1[tid] = fmaxf(s, 0.f);
    }
    __syncthreads();
    if (tid < 64) {
        float s = fpb2[tid];
        for (int k = 0; k < 128; ++k) s += fpw2[tid * 128 + k] * hid1[k];
        sf[tid] = s;
    }
    __syncthreads();
    if (tid >= 128 && tid < 192) fused[tid] = sf[tid - 128];
    __syncthreads();
    {
        float s = ffb1[tid];
        for (int k = 0; k < 192; ++k) s += ffw1[tid * 192 + k] * fused[k];
        hid2[tid] = fmaxf(s, 0.f);
    }
    __syncthreads();
    {
        float s = ffb2[tid];
        for (int k = 0; k < 256; ++k) s += ffw2[tid * 256 + k] * hid2[k];
        out[(size_t)b * 256 + tid] = s;
    }
}

// ---------------------------------------------------------------------------
extern "C" void kernel_launch(void* const* d_in, const int* in_sizes, int n_in,
                              void* d_out, int out_size, void* d_ws, size_t ws_size,
                              hipStream_t stream)
{
    const float* x    = (const float*)d_in[0];
    const float* mask = (const float*)d_in[1];
    const float* lw1 = (const float*)d_in[2];  const float* lb1 = (const float*)d_in[3];
    const float* lw2 = (const float*)d_in[4];  const float* lb2 = (const float*)d_in[5];
    const float* lw3 = (const float*)d_in[6];  const float* lb3 = (const float*)d_in[7];
    const float* sw1 = (const float*)d_in[8];  const float* sb1 = (const float*)d_in[9];
    const float* sw2 = (const float*)d_in[10]; const float* sb2 = (const float*)d_in[11];
    const float* sw3 = (const float*)d_in[12]; const float* sb3 = (const float*)d_in[13];
    const float* gw  = (const float*)d_in[14]; const float* gb  = (const float*)d_in[15];
    const float* fpw1 = (const float*)d_in[16]; const float* fpb1 = (const float*)d_in[17];
    const float* fpw2 = (const float*)d_in[18]; const float* fpb2 = (const float*)d_in[19];
    const float* ffw1 = (const float*)d_in[20]; const float* ffb1 = (const float*)d_in[21];
    const float* ffw2 = (const float*)d_in[22]; const float* ffb2 = (const float*)d_in[23];
    float* out = (float*)d_out;

    char* ws = (char*)d_ws;
    // padded NHWC intermediates (disjoint so borders are zeroed once)
    _Float16* AL = (_Float16*)ws;                          // [64][130][130][32]
    _Float16* BL = (_Float16*)(ws + 69222400);             // [64][66][66][64]
    _Float16* AS = (_Float16*)(ws + 104906752);            // [64][130][130][16]
    _Float16* BS = (_Float16*)(ws + 139517952);            // [64][66][66][32]
    size_t base = 157360128;
    float* areaA     = (float*)(ws + base);                // 256
    float* siA       = (float*)(ws + base + 256);          // 256
    float* sjA       = (float*)(ws + base + 512);          // 256
    int*   maxiA     = (int*)  (ws + base + 768);          // 256
    int*   maxjA     = (int*)  (ws + base + 1024);         // 256
    int*   miniA     = (int*)  (ws + base + 1280);         // 256
    int*   minjA     = (int*)  (ws + base + 1536);         // 256
    _Float16* W1L    = (_Float16*)(ws + base + 2048);      // 2,048
    _Float16* W1S    = (_Float16*)(ws + base + 4096);      // 2,048 (1,024 used)
    _Float16* wp2    = (_Float16*)(ws + base + 6144);      // 36,864
    _Float16* wp3    = (_Float16*)(ws + base + 43008);     // 147,456
    _Float16* wp2s   = (_Float16*)(ws + base + 190464);    // 18,432
    _Float16* wp3s   = (_Float16*)(ws + base + 208896);    // 36,864
    float* PL        = (float*)(ws + base + 245760);       // 64*8*128*4 = 262,144
    float* PS        = (float*)(ws + base + 507904);       // 64*8*64*4  = 131,072

    // stats init: area/si/sj/maxi/maxj = 0; mini/minj = huge
    hipMemsetAsync(ws + base, 0, 1280, stream);
    hipMemsetAsync(ws + base + 1280, 0x7f, 512, stream);

    // weight prep + border zeroing
    prep_all_k<<<474, 256, 0, stream>>>(lw1, sw1, lw2, lw3, sw2, sw3,
                                        W1L, W1S, wp2, wp3, wp2s, wp3s);
    zerob_all_k<<<1554, 256, 0, stream>>>(AL, BL, AS, BS);

    // ---- local branch ----
    conv1_mfma_k<32, false><<<64 * 128, 256, 0, stream>>>(
        x, W1L, lb1, AL, nullptr, nullptr, nullptr, nullptr, nullptr, nullptr, nullptr);
    convN_mfma_k<32, 64, 128, true> <<<64 * 32, 256, 0, stream>>>(AL, wp2, lb2, BL);
    convN_mfma_k<64, 128, 64, false><<<64 * 8 * 2, 256, 0, stream>>>(BL, wp3, lb3, PL);

    // ---- shape branch (conv1 also computes mask global-stats) ----
    conv1_mfma_k<16, true><<<64 * 128, 256, 0, stream>>>(
        mask, W1S, sb1, AS, areaA, siA, sjA, miniA, maxiA, minjA, maxjA);
    convN_mfma_k<16, 32, 128, true> <<<64 * 32, 256, 0, stream>>>(AS, wp2s, sb2, BS);
    convN_mfma_k<32, 64, 64, false> <<<64 * 8, 256, 0, stream>>>(BS, wp3s, sb3, PS);

    // ---- head ----
    head_k<<<64, 256, 0, stream>>>(PL, PS, areaA, siA, sjA,
                                   miniA, maxiA, minjA, maxjA, gw, gb,
                                   fpw1, fpb1, fpw2, fpb2, ffw1, ffb1, ffw2, ffb2, out);
}

// Round 13
// 270.481 us; speedup vs baseline: 1.1330x; 1.1330x over previous
//
#include <hip/hip_runtime.h>

typedef _Float16 f16x8 __attribute__((ext_vector_type(8)));
typedef float    f32x4 __attribute__((ext_vector_type(4)));

static __device__ inline f16x8 f16x8_zero() {
    f16x8 v;
#pragma unroll
    for (int j = 0; j < 8; ++j) v[j] = (_Float16)0.f;
    return v;
}

// ---------------------------------------------------------------------------
// Merged weight prep (one launch).
// conv1 split-f16: k=0..8 hi(w), 9..17 hi(w), 18..26 lo(w), 27..31 zero
//   (pairs with A rows {hi,lo,hi} -> full fp32 accuracy).
// convN: fp32 OIHW -> f16 [ch][tap][COUT][32k] (zero-pad past CIN).
// ---------------------------------------------------------------------------
static __device__ inline void prep1_elem(const float* __restrict__ w,
                                         _Float16* __restrict__ dst, int t) {
    int co = t >> 5, k = t & 31;
    _Float16 r = (_Float16)0.f;
    if (k < 27) {
        int q = k / 9, tap = k - q * 9;
        float wv = w[co * 9 + tap];
        _Float16 hi = (_Float16)wv;
        r = (q == 2) ? (_Float16)(wv - (float)hi) : hi;
    }
    dst[t] = r;
}

template<int CIN, int COUT>
static __device__ inline void prepN_elem(const float* __restrict__ w,
                                         _Float16* __restrict__ dst, int t) {
    int k = t & 31;
    int r = t >> 5;
    int co = r % COUT; r /= COUT;
    int tap = r % 9;
    int chh = r / 9;
    int ci  = chh * 32 + k;
    dst[t] = (ci < CIN) ? (_Float16)w[(co * CIN + ci) * 9 + tap] : (_Float16)0.f;
}

__global__ __launch_bounds__(256) void prep_all_k(
    const float* __restrict__ lw1, const float* __restrict__ sw1,
    const float* __restrict__ lw2, const float* __restrict__ lw3,
    const float* __restrict__ sw2, const float* __restrict__ sw3,
    _Float16* __restrict__ W1L, _Float16* __restrict__ W1S,
    _Float16* __restrict__ wp2, _Float16* __restrict__ wp3,
    _Float16* __restrict__ wp2s, _Float16* __restrict__ wp3s)
{
    int t = blockIdx.x * 256 + threadIdx.x;
    if (t < 1024)  { prep1_elem(lw1, W1L, t); return; }   t -= 1024;
    if (t < 512)   { prep1_elem(sw1, W1S, t); return; }   t -= 512;
    if (t < 18432) { prepN_elem<32, 64>(lw2, wp2, t);  return; }  t -= 18432;
    if (t < 73728) { prepN_elem<64, 128>(lw3, wp3, t); return; }  t -= 73728;
    if (t < 9216)  { prepN_elem<16, 32>(sw2, wp2s, t); return; }  t -= 9216;
    if (t < 18432) { prepN_elem<32, 64>(sw3, wp3s, t); return; }
}

// ---------------------------------------------------------------------------
// conv1: CIN=1 fp32 in [B][256][256] -> conv+bias+relu+pool ->
// f16 UNPADDED NHWC [B][128][128][COUT]. K=27 split-f16 (fp32-exact).
// 16x16 conv-pixel tile, 4 waves.
// ---------------------------------------------------------------------------
template<int COUT>
__global__ __launch_bounds__(256) void conv1_mfma_k(
    const float* __restrict__ in, const _Float16* __restrict__ W1,
    const float* __restrict__ bias, _Float16* __restrict__ out)
{
    constexpr int H = 256, TILES = H / 16, NT = COUT / 16;

    __shared__ _Float16 sHL[972];   // [0,324)=hi, [324,648)=lo, [648,972)=0

    int blk  = blockIdx.x;
    int b    = blk / (TILES * TILES);
    int tile = blk % (TILES * TILES);
    int ty0  = (tile / TILES) * 16;
    int tx0  = (tile % TILES) * 16;
    int tid  = threadIdx.x;
    int wv   = tid >> 6, l = tid & 63, cl = l & 15, kg = l >> 4;

    for (int idx = tid; idx < 324; idx += 256) {
        int row = idx / 18, col = idx - row * 18;
        int gy = ty0 - 1 + row, gx = tx0 - 1 + col;
        float v = 0.f;
        if ((unsigned)gy < (unsigned)H && (unsigned)gx < (unsigned)H)
            v = in[((size_t)b * H + gy) * H + gx];
        _Float16 hi = (_Float16)v;
        sHL[idx]       = hi;
        sHL[324 + idx] = (_Float16)(v - (float)hi);
        sHL[648 + idx] = (_Float16)0.f;
    }
    __syncthreads();

    int off8[8];
#pragma unroll
    for (int j = 0; j < 8; ++j) {
        int k = kg * 8 + j;
        int q = k / 9;
        int t = k - q * 9;
        int region = (q == 1) ? 1 : ((q == 3) ? 2 : 0);
        off8[j] = region * 324 + (t / 3) * 18 + (t % 3) + cl;
    }

    f16x8 bf[NT];
#pragma unroll
    for (int nt = 0; nt < NT; ++nt)
        bf[nt] = *(const f16x8*)&W1[(nt * 16 + cl) * 32 + kg * 8];

    f32x4 acc[4][NT];
#pragma unroll
    for (int i = 0; i < 4; ++i)
#pragma unroll
        for (int nt = 0; nt < NT; ++nt) acc[i][nt] = (f32x4){0.f, 0.f, 0.f, 0.f};

#pragma unroll
    for (int i = 0; i < 4; ++i) {
        int R = wv * 4 + i;
        f16x8 af;
#pragma unroll
        for (int j = 0; j < 8; ++j) af[j] = sHL[off8[j] + R * 18];
#pragma unroll
        for (int nt = 0; nt < NT; ++nt)
            acc[i][nt] = __builtin_amdgcn_mfma_f32_16x16x32_f16(af, bf[nt], acc[i][nt], 0, 0, 0);
    }

    int py0 = ty0 >> 1, px0 = tx0 >> 1;
#pragma unroll
    for (int i2 = 0; i2 < 2; ++i2)
#pragma unroll
        for (int j2 = 0; j2 < 2; ++j2)
#pragma unroll
            for (int nt = 0; nt < NT; ++nt) {   // nt inner: line-clustered stores
                float bv = bias[nt * 16 + cl];
                float m = fmaxf(fmaxf(acc[2 * i2][nt][2 * j2], acc[2 * i2][nt][2 * j2 + 1]),
                                fmaxf(acc[2 * i2 + 1][nt][2 * j2], acc[2 * i2 + 1][nt][2 * j2 + 1]));
                float v = fmaxf(m + bv, 0.f);
                out[(((size_t)b * 128 + py0 + wv * 2 + i2) * 128 + px0 + kg * 2 + j2) * COUT
                    + nt * 16 + cl] = (_Float16)v;
            }
}

// ---------------------------------------------------------------------------
// convN v10 = r12 compute core (XOR-swizzled unpadded LDS, conflicts=0;
// (256,2) mandatory: M8N4 acc = 128 AGPR + 128 VGPR = full 256/wave budget;
// non-atomic partials) + r6's A-path: UNPADDED NHWC input with
// bounds-checked register staging (r6's conv3 FETCH was 42 MB vs 97 MB
// with padded buffers — padding only served the abandoned gload_lds path).
// One block per (b, tile, co-group); NCH chunks: global->VGPR->swizzled
// ds_write, barrier, 9-tap MFMA loop, W per-lane from global (L2-hot,
// 2-slot rotation). Wave = 8 rows x 16 cols x NT*16 co (M8).
// LDS unit u = pos*KU + q', KU=4: q'=q^((pos>>1)&3); KU=2: q'=q^((pos>>2)&1).
// CIN=16: kg>=2 lanes read unit kg&1 (finite data x zero-padded W = 0).
// POOL=false: cross-wave LDS reduce -> one non-atomic 64-partial store.
// ---------------------------------------------------------------------------
template<int CIN, int COUT, int H, bool POOL>
__global__ __launch_bounds__(256, 2) void convN_mfma_k(
    const _Float16* __restrict__ in, const _Float16* __restrict__ wp,
    const float* __restrict__ bias, void* __restrict__ outv)
{
    constexpr int TX  = H / 16, TY = H / 32, TT = TX * TY;
    constexpr int NT  = (COUT >= 64) ? 4 : COUT / 16;
    constexpr int NG  = COUT / (NT * 16);
    constexpr int NCH = (CIN + 31) / 32;
    constexpr int KU  = (CIN >= 32) ? 4 : 2;        // 16B units per pos
    constexpr int UNITS = 612 * KU;
    constexpr int NU  = (UNITS + 255) / 256;
    static_assert(H % 32 == 0 && COUT % 16 == 0, "");

    __shared__ _Float16 sA[UNITS * 8];              // unpadded, swizzled
    __shared__ float sRed[4][64];

    int tid = threadIdx.x;
    int wv = tid >> 6, l = tid & 63, cl = l & 15, kg = l >> 4;

    int blk  = blockIdx.x;
    int bb   = blk / (TT * NG);
    int rr   = blk % (TT * NG);
    int grp  = rr / TT;
    int tl   = rr % TT;
    int ty0  = (tl / TX) * 32, tx0 = (tl % TX) * 16;
    int cog0 = grp * NT * 16;

    f32x4 acc[8][NT];
#pragma unroll
    for (int i = 0; i < 8; ++i)
#pragma unroll
        for (int nt = 0; nt < NT; ++nt) acc[i][nt] = (f32x4){0.f, 0.f, 0.f, 0.f};

    const _Float16* ibase = in + (size_t)bb * H * H * CIN;

    for (int ch = 0; ch < NCH; ++ch) {
        if (ch) __syncthreads();
        // ---- stage: bounds-checked global reads, swizzled ds_write ----
#pragma unroll
        for (int k = 0; k < NU; ++k) {
            int u = k * 256 + tid;
            if (u < UNITS) {
                int pos, q;
                if (KU == 4) { pos = u >> 2; q = (u & 3) ^ ((pos >> 1) & 3); }
                else         { pos = u >> 1; q = (u & 1) ^ ((pos >> 2) & 1); }
                int row = pos / 18, col = pos - row * 18;
                int gy = ty0 - 1 + row, gx = tx0 - 1 + col;
                f16x8 v = f16x8_zero();
                if ((unsigned)gy < (unsigned)H && (unsigned)gx < (unsigned)H)
                    v = *(const f16x8*)&ibase[((size_t)gy * H + gx) * CIN + ch * 32 + q * 8];
                *(f16x8*)&sA[(size_t)u * 8] = v;
            }
        }
        __syncthreads();

        const _Float16* wbase = wp + ((size_t)ch * 9 * COUT + cog0) * 32;
        f16x8 wreg[2][NT];
#pragma unroll
        for (int nt = 0; nt < NT; ++nt)
            wreg[0][nt] = *(const f16x8*)&wbase[(0 * COUT + nt * 16 + cl) * 32 + kg * 8];

#pragma unroll
        for (int tap = 0; tap < 9; ++tap) {
            if (tap < 8) {
#pragma unroll
                for (int nt = 0; nt < NT; ++nt)
                    wreg[(tap + 1) & 1][nt] =
                        *(const f16x8*)&wbase[((tap + 1) * COUT + nt * 16 + cl) * 32 + kg * 8];
            }
            int dy = tap / 3, dx = tap - dy * 3;
#pragma unroll
            for (int i = 0; i < 8; ++i) {
                int pos = (wv * 8 + i + dy) * 18 + cl + dx;
                int qq = (KU == 4) ? (kg ^ ((pos >> 1) & 3))
                                   : ((kg & 1) ^ ((pos >> 2) & 1));
                f16x8 af = *(const f16x8*)&sA[((size_t)pos * KU + qq) * 8];
#pragma unroll
                for (int nt = 0; nt < NT; ++nt)
                    acc[i][nt] = __builtin_amdgcn_mfma_f32_16x16x32_f16(
                        af, wreg[tap & 1][nt], acc[i][nt], 0, 0, 0);
            }
        }
    }

    if (POOL) {
        _Float16* out = (_Float16*)outv;
        constexpr int HO = H / 2;
        int py0 = ty0 >> 1, px0 = tx0 >> 1;
        float bv[NT];
#pragma unroll
        for (int nt = 0; nt < NT; ++nt) bv[nt] = bias[cog0 + nt * 16 + cl];
#pragma unroll
        for (int i2 = 0; i2 < 4; ++i2)
#pragma unroll
            for (int j2 = 0; j2 < 2; ++j2)
#pragma unroll
                for (int nt = 0; nt < NT; ++nt) {   // nt inner: line-clustered
                    float m = fmaxf(
                        fmaxf(acc[2 * i2][nt][2 * j2], acc[2 * i2][nt][2 * j2 + 1]),
                        fmaxf(acc[2 * i2 + 1][nt][2 * j2], acc[2 * i2 + 1][nt][2 * j2 + 1]));
                    float v = fmaxf(m + bv[nt], 0.f);
                    out[(((size_t)bb * HO + py0 + wv * 4 + i2) * HO + px0 + kg * 2 + j2)
                        * COUT + cog0 + nt * 16 + cl] = (_Float16)v;
                }
    } else {
        float sv[NT];
#pragma unroll
        for (int nt = 0; nt < NT; ++nt) {
            float bvv = bias[cog0 + nt * 16 + cl];
            float s = 0.f;
#pragma unroll
            for (int i = 0; i < 8; ++i)
#pragma unroll
                for (int r = 0; r < 4; ++r)
                    s += fmaxf(acc[i][nt][r] + bvv, 0.f);
            s += __shfl_xor(s, 16); s += __shfl_xor(s, 32);
            sv[nt] = s;
        }
        if (kg == 0) {
#pragma unroll
            for (int nt = 0; nt < NT; ++nt) sRed[wv][nt * 16 + cl] = sv[nt];
        }
        __syncthreads();
        if (tid < NT * 16) {
            float t4 = sRed[0][tid] + sRed[1][tid] + sRed[2][tid] + sRed[3][tid];
            ((float*)outv)[((size_t)bb * TT + tl) * COUT + cog0 + tid] = t4;
        }
    }
}

// ---------------------------------------------------------------------------
// global_stats partial: 4 blocks per image, atomic merge into raw arrays.
// ---------------------------------------------------------------------------
__global__ __launch_bounds__(256) void stats_k(const float* __restrict__ mask,
    float* __restrict__ areaA, float* __restrict__ siA, float* __restrict__ sjA,
    int* __restrict__ miniA, int* __restrict__ maxiA,
    int* __restrict__ minjA, int* __restrict__ maxjA)
{
    int blk = blockIdx.x, b = blk >> 2, part = blk & 3;
    int tid = threadIdx.x;
    const float4* m4 = (const float4*)(mask + (size_t)b * 65536);
    float area = 0.f, si = 0.f, sj = 0.f;
    int mini = 1 << 20, maxi = -1, minj = 1 << 20, maxj = -1;
    for (int i4 = part * 4096 + tid; i4 < (part + 1) * 4096; i4 += 256) {
        float4 v = m4[i4];
        int base = i4 * 4;
        int i = base >> 8, j0 = base & 255;
        float vv[4] = {v.x, v.y, v.z, v.w};
#pragma unroll
        for (int q = 0; q < 4; ++q) {
            if (vv[q] != 0.f) {
                int j = j0 + q;
                area += 1.f; si += (float)i; sj += (float)j;
                mini = min(mini, i); maxi = max(maxi, i);
                minj = min(minj, j); maxj = max(maxj, j);
            }
        }
    }
#pragma unroll
    for (int off = 32; off > 0; off >>= 1) {
        area += __shfl_down(area, off);
        si   += __shfl_down(si, off);
        sj   += __shfl_down(sj, off);
        mini  = min(mini, __shfl_down(mini, off));
        maxi  = max(maxi, __shfl_down(maxi, off));
        minj  = min(minj, __shfl_down(minj, off));
        maxj  = max(maxj, __shfl_down(maxj, off));
    }
    __shared__ float rA[4], rI[4], rJ[4];
    __shared__ int   rmi[4], rMi[4], rmj[4], rMj[4];
    if ((tid & 63) == 0) {
        int w = tid >> 6;
        rA[w] = area; rI[w] = si; rJ[w] = sj;
        rmi[w] = mini; rMi[w] = maxi; rmj[w] = minj; rMj[w] = maxj;
    }
    __syncthreads();
    if (tid == 0) {
        area = rA[0] + rA[1] + rA[2] + rA[3];
        si   = rI[0] + rI[1] + rI[2] + rI[3];
        sj   = rJ[0] + rJ[1] + rJ[2] + rJ[3];
        mini = min(min(rmi[0], rmi[1]), min(rmi[2], rmi[3]));
        maxi = max(max(rMi[0], rMi[1]), max(rMi[2], rMi[3]));
        minj = min(min(rmj[0], rmj[1]), min(rmj[2], rmj[3]));
        maxj = max(max(rMj[0], rMj[1]), max(rMj[2], rMj[3]));
        if (area > 0.f) {
            atomicAdd(&areaA[b], area);
            atomicAdd(&siA[b], si);
            atomicAdd(&sjA[b], sj);
            atomicMin(&miniA[b], mini);
            atomicMax(&maxiA[b], maxi);
            atomicMin(&minjA[b], minj);
            atomicMax(&maxjA[b], maxj);
        }
    }
}

// ---------------------------------------------------------------------------
// Fused MLP head: reduces conv3 tile-partials (8 tiles each) + global_stats.
// ---------------------------------------------------------------------------
__global__ __launch_bounds__(256) void head_k(
    const float* __restrict__ PL,         // B x 8 x 128 (tile partial sums)
    const float* __restrict__ PS,         // B x 8 x 64
    const float* __restrict__ areaA, const float* __restrict__ siA,
    const float* __restrict__ sjA,
    const int* __restrict__ miniA, const int* __restrict__ maxiA,
    const int* __restrict__ minjA, const int* __restrict__ maxjA,
    const float* __restrict__ gw, const float* __restrict__ gb,
    const float* __restrict__ fpw1, const float* __restrict__ fpb1,
    const float* __restrict__ fpw2, const float* __restrict__ fpb2,
    const float* __restrict__ ffw1, const float* __restrict__ ffb1,
    const float* __restrict__ ffw2, const float* __restrict__ ffb2,
    float* __restrict__ out)              // B x 256
{
    int b = blockIdx.x, tid = threadIdx.x;
    __shared__ float comb[80], hid1[128], sf[64], fused[192], hid2[256];
    constexpr float INV = 1.f / 4096.f;

    if (tid < 64) {
        float s = 0.f;
#pragma unroll
        for (int t = 0; t < 8; ++t) s += PS[((size_t)b * 8 + t) * 64 + tid];
        comb[tid] = s * INV;
    }
    if (tid >= 64 && tid < 80) {
        int co = tid - 64;
        float st[6] = {0.f, 0.f, 0.f, 0.f, 0.f, 0.f};
        float area = areaA[b];
        if (area > 0.f) {
            float safe = fmaxf(area, 1.f);
            float h  = (float)(maxiA[b] - miniA[b]);
            float w2 = (float)(maxjA[b] - minjA[b]);
            st[0] = (siA[b] / safe) / 256.f;
            st[1] = (sjA[b] / safe) / 256.f;
            st[2] = h / 256.f; st[3] = w2 / 256.f;
            st[4] = area / 65536.f; st[5] = h * w2 / 65536.f;
        }
        float s = gb[co];
        for (int k = 0; k < 6; ++k) s += gw[co * 6 + k] * st[k];
        comb[tid] = s;
    }
    if (tid < 128) {
        float s = 0.f;
#pragma unroll
        for (int t = 0; t < 8; ++t) s += PL[((size_t)b * 8 + t) * 128 + tid];
        fused[tid] = s * INV;
    }
    __syncthreads();
    if (tid < 128) {
        float s = fpb1[tid];
        for (int k = 0; k < 80; ++k) s += fpw1[tid * 80 + k] * comb[k];
        hid1[tid] = fmaxf(s, 0.f);
    }
    __syncthreads();
    if (tid < 64) {
        float s = fpb2[tid];
        for (int k = 0; k < 128; ++k) s += fpw2[tid * 128 + k] * hid1[k];
        sf[tid] = s;
    }
    __syncthreads();
    if (tid >= 128 && tid < 192) fused[tid] = sf[tid - 128];
    __syncthreads();
    {
        float s = ffb1[tid];
        for (int k = 0; k < 192; ++k) s += ffw1[tid * 192 + k] * fused[k];
        hid2[tid] = fmaxf(s, 0.f);
    }
    __syncthreads();
    {
        float s = ffb2[tid];
        for (int k = 0; k < 256; ++k) s += ffw2[tid * 256 + k] * hid2[k];
        out[(size_t)b * 256 + tid] = s;
    }
}

// ---------------------------------------------------------------------------
extern "C" void kernel_launch(void* const* d_in, const int* in_sizes, int n_in,
                              void* d_out, int out_size, void* d_ws, size_t ws_size,
                              hipStream_t stream)
{
    const float* x    = (const float*)d_in[0];
    const float* mask = (const float*)d_in[1];
    const float* lw1 = (const float*)d_in[2];  const float* lb1 = (const float*)d_in[3];
    const float* lw2 = (const float*)d_in[4];  const float* lb2 = (const float*)d_in[5];
    const float* lw3 = (const float*)d_in[6];  const float* lb3 = (const float*)d_in[7];
    const float* sw1 = (const float*)d_in[8];  const float* sb1 = (const float*)d_in[9];
    const float* sw2 = (const float*)d_in[10]; const float* sb2 = (const float*)d_in[11];
    const float* sw3 = (const float*)d_in[12]; const float* sb3 = (const float*)d_in[13];
    const float* gw  = (const float*)d_in[14]; const float* gb  = (const float*)d_in[15];
    const float* fpw1 = (const float*)d_in[16]; const float* fpb1 = (const float*)d_in[17];
    const float* fpw2 = (const float*)d_in[18]; const float* fpb2 = (const float*)d_in[19];
    const float* ffw1 = (const float*)d_in[20]; const float* ffb1 = (const float*)d_in[21];
    const float* ffw2 = (const float*)d_in[22]; const float* ffb2 = (const float*)d_in[23];
    float* out = (float*)d_out;

    char* ws = (char*)d_ws;
    // UNPADDED NHWC intermediates (bufA/bufB reused by both branches)
    _Float16* bufA = (_Float16*)ws;                        // [64][128][128][<=32] 67,108,864
    _Float16* bufB = (_Float16*)(ws + 67108864);           // [64][64][64][<=64]   33,554,432
    size_t base = 100663296;
    float* areaA     = (float*)(ws + base);                // 256
    float* siA       = (float*)(ws + base + 256);          // 256
    float* sjA       = (float*)(ws + base + 512);          // 256
    int*   maxiA     = (int*)  (ws + base + 768);          // 256
    int*   maxjA     = (int*)  (ws + base + 1024);         // 256
    int*   miniA     = (int*)  (ws + base + 1280);         // 256
    int*   minjA     = (int*)  (ws + base + 1536);         // 256
    _Float16* W1L    = (_Float16*)(ws + base + 2048);      // 2,048
    _Float16* W1S    = (_Float16*)(ws + base + 4096);      // 1,024 used
    _Float16* wp2    = (_Float16*)(ws + base + 6144);      // 36,864
    _Float16* wp3    = (_Float16*)(ws + base + 43008);     // 147,456
    _Float16* wp2s   = (_Float16*)(ws + base + 190464);    // 18,432
    _Float16* wp3s   = (_Float16*)(ws + base + 208896);    // 36,864
    float* PL        = (float*)(ws + base + 245760);       // 64*8*128*4 = 262,144
    float* PS        = (float*)(ws + base + 507904);       // 64*8*64*4  = 131,072

    // stats init: area/si/sj/maxi/maxj = 0; mini/minj = huge
    hipMemsetAsync(ws + base, 0, 1280, stream);
    hipMemsetAsync(ws + base + 1280, 0x7f, 512, stream);

    // merged weight prep
    prep_all_k<<<474, 256, 0, stream>>>(lw1, sw1, lw2, lw3, sw2, sw3,
                                        W1L, W1S, wp2, wp3, wp2s, wp3s);

    // ---- local branch ----
    conv1_mfma_k<32><<<64 * 256, 256, 0, stream>>>(x, W1L, lb1, bufA);
    convN_mfma_k<32, 64, 128, true> <<<64 * 32, 256, 0, stream>>>(bufA, wp2, lb2, bufB);
    convN_mfma_k<64, 128, 64, false><<<64 * 8 * 2, 256, 0, stream>>>(bufB, wp3, lb3, PL);

    // ---- shape branch (reuses bufA/bufB sequentially) ----
    conv1_mfma_k<16><<<64 * 256, 256, 0, stream>>>(mask, W1S, sb1, bufA);
    convN_mfma_k<16, 32, 128, true> <<<64 * 32, 256, 0, stream>>>(bufA, wp2s, sb2, bufB);
    convN_mfma_k<32, 64, 64, false> <<<64 * 8, 256, 0, stream>>>(bufB, wp3s, sb3, PS);

    // ---- global stats + head ----
    stats_k<<<256, 256, 0, stream>>>(mask, areaA, siA, sjA, miniA, maxiA, minjA, maxjA);
    head_k<<<64, 256, 0, stream>>>(PL, PS, areaA, siA, sjA,
                                   miniA, maxiA, minjA, maxjA, gw, gb,
                                   fpw1, fpb1, fpw2, fpb2, ffw1, ffb1, ffw2, ffb2, out);
}

// Round 14
// 262.033 us; speedup vs baseline: 1.1696x; 1.0322x over previous
//
#include <hip/hip_runtime.h>

typedef _Float16 f16x8 __attribute__((ext_vector_type(8)));
typedef float    f32x4 __attribute__((ext_vector_type(4)));

static __device__ inline f16x8 f16x8_zero() {
    f16x8 v;
#pragma unroll
    for (int j = 0; j < 8; ++j) v[j] = (_Float16)0.f;
    return v;
}

// ---------------------------------------------------------------------------
// Merged weight prep (one launch).
// conv1 split-f16: k=0..8 hi(w), 9..17 hi(w), 18..26 lo(w), 27..31 zero
//   (pairs with A rows {hi,lo,hi} -> full fp32 accuracy).
// convN: fp32 OIHW -> f16 [ch][tap][COUT][32k] (zero-pad past CIN).
// ---------------------------------------------------------------------------
static __device__ inline void prep1_elem(const float* __restrict__ w,
                                         _Float16* __restrict__ dst, int t) {
    int co = t >> 5, k = t & 31;
    _Float16 r = (_Float16)0.f;
    if (k < 27) {
        int q = k / 9, tap = k - q * 9;
        float wv = w[co * 9 + tap];
        _Float16 hi = (_Float16)wv;
        r = (q == 2) ? (_Float16)(wv - (float)hi) : hi;
    }
    dst[t] = r;
}

template<int CIN, int COUT>
static __device__ inline void prepN_elem(const float* __restrict__ w,
                                         _Float16* __restrict__ dst, int t) {
    int k = t & 31;
    int r = t >> 5;
    int co = r % COUT; r /= COUT;
    int tap = r % 9;
    int chh = r / 9;
    int ci  = chh * 32 + k;
    dst[t] = (ci < CIN) ? (_Float16)w[(co * CIN + ci) * 9 + tap] : (_Float16)0.f;
}

__global__ __launch_bounds__(256) void prep_all_k(
    const float* __restrict__ lw1, const float* __restrict__ sw1,
    const float* __restrict__ lw2, const float* __restrict__ lw3,
    const float* __restrict__ sw2, const float* __restrict__ sw3,
    _Float16* __restrict__ W1L, _Float16* __restrict__ W1S,
    _Float16* __restrict__ wp2, _Float16* __restrict__ wp3,
    _Float16* __restrict__ wp2s, _Float16* __restrict__ wp3s)
{
    int t = blockIdx.x * 256 + threadIdx.x;
    if (t < 1024)  { prep1_elem(lw1, W1L, t); return; }   t -= 1024;
    if (t < 512)   { prep1_elem(sw1, W1S, t); return; }   t -= 512;
    if (t < 18432) { prepN_elem<32, 64>(lw2, wp2, t);  return; }  t -= 18432;
    if (t < 73728) { prepN_elem<64, 128>(lw3, wp3, t); return; }  t -= 73728;
    if (t < 9216)  { prepN_elem<16, 32>(sw2, wp2s, t); return; }  t -= 9216;
    if (t < 18432) { prepN_elem<32, 64>(sw3, wp3s, t); return; }
}

// ---------------------------------------------------------------------------
// conv1: CIN=1 fp32 in [B][256][256] -> conv+bias+relu+pool ->
// f16 UNPADDED NHWC [B][128][128][COUT]. K=27 split-f16 (fp32-exact).
// 16x16 conv-pixel tile, 4 waves.
// ---------------------------------------------------------------------------
template<int COUT>
__global__ __launch_bounds__(256) void conv1_mfma_k(
    const float* __restrict__ in, const _Float16* __restrict__ W1,
    const float* __restrict__ bias, _Float16* __restrict__ out)
{
    constexpr int H = 256, TILES = H / 16, NT = COUT / 16;

    __shared__ _Float16 sHL[972];   // [0,324)=hi, [324,648)=lo, [648,972)=0

    int blk  = blockIdx.x;
    int b    = blk / (TILES * TILES);
    int tile = blk % (TILES * TILES);
    int ty0  = (tile / TILES) * 16;
    int tx0  = (tile % TILES) * 16;
    int tid  = threadIdx.x;
    int wv   = tid >> 6, l = tid & 63, cl = l & 15, kg = l >> 4;

    for (int idx = tid; idx < 324; idx += 256) {
        int row = idx / 18, col = idx - row * 18;
        int gy = ty0 - 1 + row, gx = tx0 - 1 + col;
        float v = 0.f;
        if ((unsigned)gy < (unsigned)H && (unsigned)gx < (unsigned)H)
            v = in[((size_t)b * H + gy) * H + gx];
        _Float16 hi = (_Float16)v;
        sHL[idx]       = hi;
        sHL[324 + idx] = (_Float16)(v - (float)hi);
        sHL[648 + idx] = (_Float16)0.f;
    }
    __syncthreads();

    int off8[8];
#pragma unroll
    for (int j = 0; j < 8; ++j) {
        int k = kg * 8 + j;
        int q = k / 9;
        int t = k - q * 9;
        int region = (q == 1) ? 1 : ((q == 3) ? 2 : 0);
        off8[j] = region * 324 + (t / 3) * 18 + (t % 3) + cl;
    }

    f16x8 bf[NT];
#pragma unroll
    for (int nt = 0; nt < NT; ++nt)
        bf[nt] = *(const f16x8*)&W1[(nt * 16 + cl) * 32 + kg * 8];

    f32x4 acc[4][NT];
#pragma unroll
    for (int i = 0; i < 4; ++i)
#pragma unroll
        for (int nt = 0; nt < NT; ++nt) acc[i][nt] = (f32x4){0.f, 0.f, 0.f, 0.f};

#pragma unroll
    for (int i = 0; i < 4; ++i) {
        int R = wv * 4 + i;
        f16x8 af;
#pragma unroll
        for (int j = 0; j < 8; ++j) af[j] = sHL[off8[j] + R * 18];
#pragma unroll
        for (int nt = 0; nt < NT; ++nt)
            acc[i][nt] = __builtin_amdgcn_mfma_f32_16x16x32_f16(af, bf[nt], acc[i][nt], 0, 0, 0);
    }

    int py0 = ty0 >> 1, px0 = tx0 >> 1;
#pragma unroll
    for (int i2 = 0; i2 < 2; ++i2)
#pragma unroll
        for (int j2 = 0; j2 < 2; ++j2)
#pragma unroll
            for (int nt = 0; nt < NT; ++nt) {   // nt inner: line-clustered stores
                float bv = bias[nt * 16 + cl];
                float m = fmaxf(fmaxf(acc[2 * i2][nt][2 * j2], acc[2 * i2][nt][2 * j2 + 1]),
                                fmaxf(acc[2 * i2 + 1][nt][2 * j2], acc[2 * i2 + 1][nt][2 * j2 + 1]));
                float v = fmaxf(m + bv, 0.f);
                out[(((size_t)b * 128 + py0 + wv * 2 + i2) * 128 + px0 + kg * 2 + j2) * COUT
                    + nt * 16 + cl] = (_Float16)v;
            }
}

// ---------------------------------------------------------------------------
// convN v11 = r6's fast core restored + r13's safe adds.
//  - LDS: LINEAR padded layout LDA=44 (KU=4) / 22 (KU=2) halves per pos —
//    r6 measured 64us vs 79us with the XOR-swizzle (whose per-read qq math
//    sat in the MFMA-critical path); ~2-way conflicts are free (m136).
//  - grp INNERMOST in block order: the NG blocks sharing an A-tile are now
//    adjacent -> second co-group pass L2-hits (conv3 FETCH ~halves).
//  - (256,2) mandatory: M8N4 acc = 128 AGPR + 128 VGPR = full 256 budget.
//  - Non-atomic partials for POOL=false; bounds-checked staging; unpadded
//    NHWC input; W per-lane from global (L2-hot), 2-slot tap rotation.
// ---------------------------------------------------------------------------
template<int CIN, int COUT, int H, bool POOL>
__global__ __launch_bounds__(256, 2) void convN_mfma_k(
    const _Float16* __restrict__ in, const _Float16* __restrict__ wp,
    const float* __restrict__ bias, void* __restrict__ outv)
{
    constexpr int TX  = H / 16, TY = H / 32, TT = TX * TY;
    constexpr int NT  = (COUT >= 64) ? 4 : COUT / 16;
    constexpr int NG  = COUT / (NT * 16);
    constexpr int NCH = (CIN + 31) / 32;
    constexpr int KU  = (CIN >= 32) ? 4 : 2;        // 16B units per pos
    constexpr int LDA = KU * 8 + ((KU == 4) ? 12 : 6);  // 44 / 22 halves
    constexpr int UNITS = 612 * KU;
    constexpr int NU  = (UNITS + 255) / 256;
    static_assert(H % 32 == 0 && COUT % 16 == 0, "");

    __shared__ _Float16 sA[612 * LDA];
    __shared__ float sRed[4][64];

    int tid = threadIdx.x;
    int wv = tid >> 6, l = tid & 63, cl = l & 15, kg = l >> 4;

    int blk  = blockIdx.x;
    int bb   = blk / (TT * NG);
    int rr   = blk % (TT * NG);
    int tl   = rr / NG;                 // grp innermost: A-tile shared by
    int grp  = rr % NG;                 // adjacent blocks -> L2 reuse
    int ty0  = (tl / TX) * 32, tx0 = (tl % TX) * 16;
    int cog0 = grp * NT * 16;

    f32x4 acc[8][NT];
#pragma unroll
    for (int i = 0; i < 8; ++i)
#pragma unroll
        for (int nt = 0; nt < NT; ++nt) acc[i][nt] = (f32x4){0.f, 0.f, 0.f, 0.f};

    const _Float16* ibase = in + (size_t)bb * H * H * CIN;

    for (int ch = 0; ch < NCH; ++ch) {
        if (ch) __syncthreads();
        // ---- stage: bounds-checked coalesced reads, linear padded ds_write ----
#pragma unroll
        for (int k = 0; k < NU; ++k) {
            int u = k * 256 + tid;
            if (u < UNITS) {
                int pos = u / KU, q = u % KU;
                int row = pos / 18, col = pos - row * 18;
                int gy = ty0 - 1 + row, gx = tx0 - 1 + col;
                f16x8 v = f16x8_zero();
                if ((unsigned)gy < (unsigned)H && (unsigned)gx < (unsigned)H)
                    v = *(const f16x8*)&ibase[((size_t)gy * H + gx) * CIN + ch * 32 + q * 8];
                *(f16x8*)&sA[pos * LDA + q * 8] = v;
            }
        }
        __syncthreads();

        const _Float16* wbase = wp + ((size_t)ch * 9 * COUT + cog0) * 32;
        f16x8 wreg[2][NT];
#pragma unroll
        for (int nt = 0; nt < NT; ++nt)
            wreg[0][nt] = *(const f16x8*)&wbase[(0 * COUT + nt * 16 + cl) * 32 + kg * 8];

#pragma unroll
        for (int tap = 0; tap < 9; ++tap) {
            if (tap < 8) {
#pragma unroll
                for (int nt = 0; nt < NT; ++nt)
                    wreg[(tap + 1) & 1][nt] =
                        *(const f16x8*)&wbase[((tap + 1) * COUT + nt * 16 + cl) * 32 + kg * 8];
            }
            int dy = tap / 3, dx = tap - dy * 3;
            int kq = (KU == 4) ? kg : (kg & 1);
#pragma unroll
            for (int i = 0; i < 8; ++i) {
                f16x8 af = *(const f16x8*)&sA[((wv * 8 + i + dy) * 18 + cl + dx) * LDA + kq * 8];
#pragma unroll
                for (int nt = 0; nt < NT; ++nt)
                    acc[i][nt] = __builtin_amdgcn_mfma_f32_16x16x32_f16(
                        af, wreg[tap & 1][nt], acc[i][nt], 0, 0, 0);
            }
        }
    }

    if (POOL) {
        _Float16* out = (_Float16*)outv;
        constexpr int HO = H / 2;
        int py0 = ty0 >> 1, px0 = tx0 >> 1;
        float bv[NT];
#pragma unroll
        for (int nt = 0; nt < NT; ++nt) bv[nt] = bias[cog0 + nt * 16 + cl];
#pragma unroll
        for (int i2 = 0; i2 < 4; ++i2)
#pragma unroll
            for (int j2 = 0; j2 < 2; ++j2)
#pragma unroll
                for (int nt = 0; nt < NT; ++nt) {   // nt inner: line-clustered
                    float m = fmaxf(
                        fmaxf(acc[2 * i2][nt][2 * j2], acc[2 * i2][nt][2 * j2 + 1]),
                        fmaxf(acc[2 * i2 + 1][nt][2 * j2], acc[2 * i2 + 1][nt][2 * j2 + 1]));
                    float v = fmaxf(m + bv[nt], 0.f);
                    out[(((size_t)bb * HO + py0 + wv * 4 + i2) * HO + px0 + kg * 2 + j2)
                        * COUT + cog0 + nt * 16 + cl] = (_Float16)v;
                }
    } else {
        float sv[NT];
#pragma unroll
        for (int nt = 0; nt < NT; ++nt) {
            float bvv = bias[cog0 + nt * 16 + cl];
            float s = 0.f;
#pragma unroll
            for (int i = 0; i < 8; ++i)
#pragma unroll
                for (int r = 0; r < 4; ++r)
                    s += fmaxf(acc[i][nt][r] + bvv, 0.f);
            s += __shfl_xor(s, 16); s += __shfl_xor(s, 32);
            sv[nt] = s;
        }
        if (kg == 0) {
#pragma unroll
            for (int nt = 0; nt < NT; ++nt) sRed[wv][nt * 16 + cl] = sv[nt];
        }
        __syncthreads();
        if (tid < NT * 16) {
            float t4 = sRed[0][tid] + sRed[1][tid] + sRed[2][tid] + sRed[3][tid];
            ((float*)outv)[((size_t)bb * TT + tl) * COUT + cog0 + tid] = t4;
        }
    }
}

// ---------------------------------------------------------------------------
// global_stats partial: 4 blocks per image, atomic merge into raw arrays.
// ---------------------------------------------------------------------------
__global__ __launch_bounds__(256) void stats_k(const float* __restrict__ mask,
    float* __restrict__ areaA, float* __restrict__ siA, float* __restrict__ sjA,
    int* __restrict__ miniA, int* __restrict__ maxiA,
    int* __restrict__ minjA, int* __restrict__ maxjA)
{
    int blk = blockIdx.x, b = blk >> 2, part = blk & 3;
    int tid = threadIdx.x;
    const float4* m4 = (const float4*)(mask + (size_t)b * 65536);
    float area = 0.f, si = 0.f, sj = 0.f;
    int mini = 1 << 20, maxi = -1, minj = 1 << 20, maxj = -1;
    for (int i4 = part * 4096 + tid; i4 < (part + 1) * 4096; i4 += 256) {
        float4 v = m4[i4];
        int base = i4 * 4;
        int i = base >> 8, j0 = base & 255;
        float vv[4] = {v.x, v.y, v.z, v.w};
#pragma unroll
        for (int q = 0; q < 4; ++q) {
            if (vv[q] != 0.f) {
                int j = j0 + q;
                area += 1.f; si += (float)i; sj += (float)j;
                mini = min(mini, i); maxi = max(maxi, i);
                minj = min(minj, j); maxj = max(maxj, j);
            }
        }
    }
#pragma unroll
    for (int off = 32; off > 0; off >>= 1) {
        area += __shfl_down(area, off);
        si   += __shfl_down(si, off);
        sj   += __shfl_down(sj, off);
        mini  = min(mini, __shfl_down(mini, off));
        maxi  = max(maxi, __shfl_down(maxi, off));
        minj  = min(minj, __shfl_down(minj, off));
        maxj  = max(maxj, __shfl_down(maxj, off));
    }
    __shared__ float rA[4], rI[4], rJ[4];
    __shared__ int   rmi[4], rMi[4], rmj[4], rMj[4];
    if ((tid & 63) == 0) {
        int w = tid >> 6;
        rA[w] = area; rI[w] = si; rJ[w] = sj;
        rmi[w] = mini; rMi[w] = maxi; rmj[w] = minj; rMj[w] = maxj;
    }
    __syncthreads();
    if (tid == 0) {
        area = rA[0] + rA[1] + rA[2] + rA[3];
        si   = rI[0] + rI[1] + rI[2] + rI[3];
        sj   = rJ[0] + rJ[1] + rJ[2] + rJ[3];
        mini = min(min(rmi[0], rmi[1]), min(rmi[2], rmi[3]));
        maxi = max(max(rMi[0], rMi[1]), max(rMi[2], rMi[3]));
        minj = min(min(rmj[0], rmj[1]), min(rmj[2], rmj[3]));
        maxj = max(max(rMj[0], rMj[1]), max(rMj[2], rMj[3]));
        if (area > 0.f) {
            atomicAdd(&areaA[b], area);
            atomicAdd(&siA[b], si);
            atomicAdd(&sjA[b], sj);
            atomicMin(&miniA[b], mini);
            atomicMax(&maxiA[b], maxi);
            atomicMin(&minjA[b], minj);
            atomicMax(&maxjA[b], maxj);
        }
    }
}

// ---------------------------------------------------------------------------
// Fused MLP head: reduces conv3 tile-partials (8 tiles each) + global_stats.
// ---------------------------------------------------------------------------
__global__ __launch_bounds__(256) void head_k(
    const float* __restrict__ PL,         // B x 8 x 128 (tile partial sums)
    const float* __restrict__ PS,         // B x 8 x 64
    const float* __restrict__ areaA, const float* __restrict__ siA,
    const float* __restrict__ sjA,
    const int* __restrict__ miniA, const int* __restrict__ maxiA,
    const int* __restrict__ minjA, const int* __restrict__ maxjA,
    const float* __restrict__ gw, const float* __restrict__ gb,
    const float* __restrict__ fpw1, const float* __restrict__ fpb1,
    const float* __restrict__ fpw2, const float* __restrict__ fpb2,
    const float* __restrict__ ffw1, const float* __restrict__ ffb1,
    const float* __restrict__ ffw2, const float* __restrict__ ffb2,
    float* __restrict__ out)              // B x 256
{
    int b = blockIdx.x, tid = threadIdx.x;
    __shared__ float comb[80], hid1[128], sf[64], fused[192], hid2[256];
    constexpr float INV = 1.f / 4096.f;

    if (tid < 64) {
        float s = 0.f;
#pragma unroll
        for (int t = 0; t < 8; ++t) s += PS[((size_t)b * 8 + t) * 64 + tid];
        comb[tid] = s * INV;
    }
    if (tid >= 64 && tid < 80) {
        int co = tid - 64;
        float st[6] = {0.f, 0.f, 0.f, 0.f, 0.f, 0.f};
        float area = areaA[b];
        if (area > 0.f) {
            float safe = fmaxf(area, 1.f);
            float h  = (float)(maxiA[b] - miniA[b]);
            float w2 = (float)(maxjA[b] - minjA[b]);
            st[0] = (siA[b] / safe) / 256.f;
            st[1] = (sjA[b] / safe) / 256.f;
            st[2] = h / 256.f; st[3] = w2 / 256.f;
            st[4] = area / 65536.f; st[5] = h * w2 / 65536.f;
        }
        float s = gb[co];
        for (int k = 0; k < 6; ++k) s += gw[co * 6 + k] * st[k];
        comb[tid] = s;
    }
    if (tid < 128) {
        float s = 0.f;
#pragma unroll
        for (int t = 0; t < 8; ++t) s += PL[((size_t)b * 8 + t) * 128 + tid];
        fused[tid] = s * INV;
    }
    __syncthreads();
    if (tid < 128) {
        float s = fpb1[tid];
        for (int k = 0; k < 80; ++k) s += fpw1[tid * 80 + k] * comb[k];
        hid1[tid] = fmaxf(s, 0.f);
    }
    __syncthreads();
    if (tid < 64) {
        float s = fpb2[tid];
        for (int k = 0; k < 128; ++k) s += fpw2[tid * 128 + k] * hid1[k];
        sf[tid] = s;
    }
    __syncthreads();
    if (tid >= 128 && tid < 192) fused[tid] = sf[tid - 128];
    __syncthreads();
    {
        float s = ffb1[tid];
        for (int k = 0; k < 192; ++k) s += ffw1[tid * 192 + k] * fused[k];
        hid2[tid] = fmaxf(s, 0.f);
    }
    __syncthreads();
    {
        float s = ffb2[tid];
        for (int k = 0; k < 256; ++k) s += ffw2[tid * 256 + k] * hid2[k];
        out[(size_t)b * 256 + tid] = s;
    }
}

// ---------------------------------------------------------------------------
extern "C" void kernel_launch(void* const* d_in, const int* in_sizes, int n_in,
                              void* d_out, int out_size, void* d_ws, size_t ws_size,
                              hipStream_t stream)
{
    const float* x    = (const float*)d_in[0];
    const float* mask = (const float*)d_in[1];
    const float* lw1 = (const float*)d_in[2];  const float* lb1 = (const float*)d_in[3];
    const float* lw2 = (const float*)d_in[4];  const float* lb2 = (const float*)d_in[5];
    const float* lw3 = (const float*)d_in[6];  const float* lb3 = (const float*)d_in[7];
    const float* sw1 = (const float*)d_in[8];  const float* sb1 = (const float*)d_in[9];
    const float* sw2 = (const float*)d_in[10]; const float* sb2 = (const float*)d_in[11];
    const float* sw3 = (const float*)d_in[12]; const float* sb3 = (const float*)d_in[13];
    const float* gw  = (const float*)d_in[14]; const float* gb  = (const float*)d_in[15];
    const float* fpw1 = (const float*)d_in[16]; const float* fpb1 = (const float*)d_in[17];
    const float* fpw2 = (const float*)d_in[18]; const float* fpb2 = (const float*)d_in[19];
    const float* ffw1 = (const float*)d_in[20]; const float* ffb1 = (const float*)d_in[21];
    const float* ffw2 = (const float*)d_in[22]; const float* ffb2 = (const float*)d_in[23];
    float* out = (float*)d_out;

    char* ws = (char*)d_ws;
    // UNPADDED NHWC intermediates (bufA/bufB reused by both branches)
    _Float16* bufA = (_Float16*)ws;                        // [64][128][128][<=32] 67,108,864
    _Float16* bufB = (_Float16*)(ws + 67108864);           // [64][64][64][<=64]   33,554,432
    size_t base = 100663296;
    float* areaA     = (float*)(ws + base);                // 256
    float* siA       = (float*)(ws + base + 256);          // 256
    float* sjA       = (float*)(ws + base + 512);          // 256
    int*   maxiA     = (int*)  (ws + base + 768);          // 256
    int*   maxjA     = (int*)  (ws + base + 1024);         // 256
    int*   miniA     = (int*)  (ws + base + 1280);         // 256
    int*   minjA     = (int*)  (ws + base + 1536);         // 256
    _Float16* W1L    = (_Float16*)(ws + base + 2048);      // 2,048
    _Float16* W1S    = (_Float16*)(ws + base + 4096);      // 1,024 used
    _Float16* wp2    = (_Float16*)(ws + base + 6144);      // 36,864
    _Float16* wp3    = (_Float16*)(ws + base + 43008);     // 147,456
    _Float16* wp2s   = (_Float16*)(ws + base + 190464);    // 18,432
    _Float16* wp3s   = (_Float16*)(ws + base + 208896);    // 36,864
    float* PL        = (float*)(ws + base + 245760);       // 64*8*128*4 = 262,144
    float* PS        = (float*)(ws + base + 507904);       // 64*8*64*4  = 131,072

    // stats init: area/si/sj/maxi/maxj = 0; mini/minj = huge
    hipMemsetAsync(ws + base, 0, 1280, stream);
    hipMemsetAsync(ws + base + 1280, 0x7f, 512, stream);

    // merged weight prep
    prep_all_k<<<474, 256, 0, stream>>>(lw1, sw1, lw2, lw3, sw2, sw3,
                                        W1L, W1S, wp2, wp3, wp2s, wp3s);

    // ---- local branch ----
    conv1_mfma_k<32><<<64 * 256, 256, 0, stream>>>(x, W1L, lb1, bufA);
    convN_mfma_k<32, 64, 128, true> <<<64 * 32, 256, 0, stream>>>(bufA, wp2, lb2, bufB);
    convN_mfma_k<64, 128, 64, false><<<64 * 8 * 2, 256, 0, stream>>>(bufB, wp3, lb3, PL);

    // ---- shape branch (reuses bufA/bufB sequentially) ----
    conv1_mfma_k<16><<<64 * 256, 256, 0, stream>>>(mask, W1S, sb1, bufA);
    convN_mfma_k<16, 32, 128, true> <<<64 * 32, 256, 0, stream>>>(bufA, wp2s, sb2, bufB);
    convN_mfma_k<32, 64, 64, false> <<<64 * 8, 256, 0, stream>>>(bufB, wp3s, sb3, PS);

    // ---- global stats + head ----
    stats_k<<<256, 256, 0, stream>>>(mask, areaA, siA, sjA, miniA, maxiA, minjA, maxjA);
    head_k<<<64, 256, 0, stream>>>(PL, PS, areaA, siA, sjA,
                                   miniA, maxiA, minjA, maxjA, gw, gb,
                                   fpw1, fpb1, fpw2, fpb2, ffw1, ffb1, ffw2, ffb2, out);
}